// Round 2
// baseline (4164.082 us; speedup 1.0000x reference)
//
#include <hip/hip_runtime.h>
#include <hip/hip_bf16.h>
#include <stdint.h>

// TextRNN: 2-layer tanh RNN. B=128,T=512,H=512,E=256,V=32000.
// Plan:
//   k_init : zero h-state double buffers + group flags (ws)
//   k_cw   : CW[v][j] = sum_e C[v][e]*W_ax[j][e]  (bf16, 32MB in ws) -- hoists x-proj out of scan
//   k_scan : 8 groups (16 batch rows) x 8 member blocks (64 cols). Weights bf16 in LDS (128KB/blk).
//            State circulates via L2 in MFMA-A-fragment layout; flag barriers (2/step).
//   k_out  : out = h1_final @ W_out.T + b_out  (128x32000x512 MFMA)
//
// R1 deadlock post-mortem: group_signal wrote f[0] for every member; wait polls
// f[0..7]. Fixed: signal f[mem]. Added bounded spin so protocol bugs fail fast.

#define VOCAB 32000
#define EMB   256
#define HID   512
#define BATCH 128
#define SEQ   512
#define GBUF_ELEMS 8192   // per-group h buffer: 64 units * 16 rows * 8 = HID*16 bf16

typedef __attribute__((ext_vector_type(8))) short bf16x8;
typedef __attribute__((ext_vector_type(4))) float f32x4;

__device__ inline short f2bf(float f) {
  union { float f; uint32_t u; } v; v.f = f;
  uint32_t u = v.u;
  uint32_t r = (u + 0x7FFFu + ((u >> 16) & 1u)) >> 16;
  return (short)r;
}
__device__ inline float bf2f(unsigned short s) {
  union { uint32_t u; float f; } v; v.u = ((uint32_t)s) << 16;
  return v.f;
}
__device__ inline bf16x8 cvt8(f32x4 x0, f32x4 x1) {
  bf16x8 r;
  r[0]=f2bf(x0[0]); r[1]=f2bf(x0[1]); r[2]=f2bf(x0[2]); r[3]=f2bf(x0[3]);
  r[4]=f2bf(x1[0]); r[5]=f2bf(x1[1]); r[6]=f2bf(x1[2]); r[7]=f2bf(x1[3]);
  return r;
}
__device__ inline f32x4 mfma16(bf16x8 a, bf16x8 b, f32x4 c) {
  return __builtin_amdgcn_mfma_f32_16x16x32_bf16(a, b, c, 0, 0, 0);
}
__device__ inline float fast_tanh(float x) {
  x = fminf(30.f, fmaxf(-30.f, x));
  float e = __expf(2.f * x);
  return (e - 1.f) * __builtin_amdgcn_rcpf(e + 1.f);
}

// ---- group barrier helpers (8 member blocks, monotonic flags, no reset) ----
__device__ inline void group_wait(const unsigned* f, unsigned target) {
  if (threadIdx.x < 8) {
    int guard = 0;
    while (__hip_atomic_load(f + threadIdx.x, __ATOMIC_ACQUIRE, __HIP_MEMORY_SCOPE_AGENT) < target) {
      __builtin_amdgcn_s_sleep(1);
      if (++guard > 50000000) break;   // fail visibly, don't hang the harness
    }
  }
  __syncthreads();
}
__device__ inline void group_signal(unsigned* f, int mem, unsigned val) {
  __syncthreads();  // all waves' stores drained (vmcnt 0) before the release
  if (threadIdx.x == 0)
    __hip_atomic_store(f + mem, val, __ATOMIC_RELEASE, __HIP_MEMORY_SCOPE_AGENT);
}

__global__ void k_init(unsigned* __restrict__ p, int n) {
  int i = blockIdx.x * 256 + threadIdx.x;
  if (i < n) p[i] = 0u;
}

// ---- CW = C @ W_ax.T  (M=32000, N=512, K=256), bf16 out ----
__global__ void __launch_bounds__(256) k_cw(const float* __restrict__ C,
                                            const float* __restrict__ Wax,
                                            unsigned short* __restrict__ CW) {
  const int tid = threadIdx.x, lane = tid & 63, wv = tid >> 6;
  const int l15 = lane & 15, l4 = lane >> 4;
  const int row = blockIdx.x * 64 + wv * 16 + l15;
  bf16x8 a[8];
  const float* crow = C + (size_t)row * EMB;
#pragma unroll
  for (int s = 0; s < 8; ++s) {
    const f32x4* p = (const f32x4*)(crow + s * 32 + l4 * 8);
    a[s] = cvt8(p[0], p[1]);
  }
  const int row_o_base = blockIdx.x * 64 + wv * 16 + l4 * 4;
  for (int ct = 0; ct < 8; ++ct) {
    f32x4 acc[4];
#pragma unroll
    for (int nf = 0; nf < 4; ++nf) acc[nf] = (f32x4){0.f, 0.f, 0.f, 0.f};
#pragma unroll
    for (int s = 0; s < 8; ++s) {
#pragma unroll
      for (int nf = 0; nf < 4; ++nf) {
        int col = ct * 64 + nf * 16 + l15;
        const f32x4* bp = (const f32x4*)(Wax + (size_t)col * EMB + s * 32 + l4 * 8);
        bf16x8 b = cvt8(bp[0], bp[1]);
        acc[nf] = mfma16(a[s], b, acc[nf]);
      }
    }
#pragma unroll
    for (int nf = 0; nf < 4; ++nf) {
      int col = ct * 64 + nf * 16 + l15;
#pragma unroll
      for (int r = 0; r < 4; ++r)
        CW[(size_t)(row_o_base + r) * HID + col] = (unsigned short)f2bf(acc[nf][r]);
    }
  }
}

// ---- the recurrent scan ----
__global__ void __launch_bounds__(256, 1) k_scan(
    const int* __restrict__ X, const float* __restrict__ Waa, const float* __restrict__ Wal,
    const float* __restrict__ ba, const unsigned short* __restrict__ CW,
    unsigned short* __restrict__ h0buf, unsigned short* __restrict__ h1buf,
    unsigned* __restrict__ flags) {
  extern __shared__ unsigned short lds[];
  unsigned short* ldsWaa = lds;              // [64][512] bf16, 16B-unit swizzled
  unsigned short* ldsWal = lds + 64 * 512;
  const int tid = threadIdx.x, lane = tid & 63, wv = tid >> 6;
  const int l15 = lane & 15, l4 = lane >> 4;
  const int g = blockIdx.x & 7, mem = blockIdx.x >> 3;  // group -> same XCD (b%8 heuristic)
  const int colslice = mem * 64;

  // stage weight slices (rows colslice..colslice+63) f32 -> bf16 LDS, swizzled
  for (int c = tid; c < 64 * 64; c += 256) {
    int row = c >> 6, u = c & 63, us = u ^ (row & 7);
    {
      const f32x4* p = (const f32x4*)(Waa + (size_t)(colslice + row) * HID + u * 8);
      *(bf16x8*)(ldsWaa + row * 512 + us * 8) = cvt8(p[0], p[1]);
    }
    {
      const f32x4* p = (const f32x4*)(Wal + (size_t)(colslice + row) * HID + u * 8);
      *(bf16x8*)(ldsWal + row * 512 + us * 8) = cvt8(p[0], p[1]);
    }
  }
  const int jloc = colslice + wv * 16 + l15;   // this lane's output col (0..511)
  const float bav = ba[jloc];
  const int wrow = wv * 16 + l15;              // LDS weight row (0..63)
  const int wbase = wrow * 512;
  const int wswz = wrow & 7;
  const int aoff = l4 * 128 + l15 * 8;         // A-frag per-lane offset (elems)
  const int wunit = ((jloc >> 3) * 128) + (jloc & 7);  // D write base (elems)
  unsigned* f0 = flags + g * 32;
  unsigned* f1 = flags + g * 32 + 16;
  unsigned short* h0base = h0buf + g * GBUF_ELEMS;
  unsigned short* h1base = h1buf + g * GBUF_ELEMS;
  const int brow0 = g * 16 + l4 * 4;           // batch rows covered by this lane's D regs
  __syncthreads();

  for (int t = 0; t < SEQ; ++t) {
    const int par = t & 1, parp = par ^ 1;
    group_wait(f1, (unsigned)t);               // all members finished layer1(t-1)

    // ---- layer 0: h0 = tanh(CW[x_t] + m0 @ Waa^T + b) ----
    float cw[4];
#pragma unroll
    for (int r = 0; r < 4; ++r) {
      int idx = X[(size_t)(brow0 + r) * SEQ + t];
      cw[r] = bf2f((unsigned short)CW[(size_t)idx * HID + jloc]);
    }
    f32x4 acc = (f32x4){0.f, 0.f, 0.f, 0.f};
    const unsigned short* A0 = h0base + parp * (8 * GBUF_ELEMS) + aoff;
#pragma unroll
    for (int s = 0; s < 16; ++s) {
      bf16x8 a = *(const bf16x8*)(A0 + s * 512);
      bf16x8 b = *(const bf16x8*)(ldsWaa + wbase + (((s * 4 + l4) ^ wswz) * 8));
      acc = mfma16(a, b, acc);
    }
    unsigned short* W0 = h0base + par * (8 * GBUF_ELEMS) + wunit;
#pragma unroll
    for (int r = 0; r < 4; ++r) {
      float h = fast_tanh(acc[r] + cw[r] + bav);
      W0[(l4 * 4 + r) * 8] = (unsigned short)f2bf(h);
    }
    group_signal(f0, mem, (unsigned)(t + 1));
    group_wait(f0, (unsigned)(t + 1));

    // ---- layer 1: h1 = tanh(h0 @ Wal^T + m1 @ Waa^T + b) ----
    f32x4 acc1 = (f32x4){0.f, 0.f, 0.f, 0.f};
    const unsigned short* A1 = h0base + par * (8 * GBUF_ELEMS) + aoff;
    const unsigned short* A2 = h1base + parp * (8 * GBUF_ELEMS) + aoff;
#pragma unroll
    for (int s = 0; s < 16; ++s) {
      bf16x8 a = *(const bf16x8*)(A1 + s * 512);
      bf16x8 b = *(const bf16x8*)(ldsWal + wbase + (((s * 4 + l4) ^ wswz) * 8));
      acc1 = mfma16(a, b, acc1);
    }
#pragma unroll
    for (int s = 0; s < 16; ++s) {
      bf16x8 a = *(const bf16x8*)(A2 + s * 512);
      bf16x8 b = *(const bf16x8*)(ldsWaa + wbase + (((s * 4 + l4) ^ wswz) * 8));
      acc1 = mfma16(a, b, acc1);
    }
    unsigned short* W1 = h1base + par * (8 * GBUF_ELEMS) + wunit;
#pragma unroll
    for (int r = 0; r < 4; ++r) {
      float h = fast_tanh(acc1[r] + bav);
      W1[(l4 * 4 + r) * 8] = (unsigned short)f2bf(h);
    }
    group_signal(f1, mem, (unsigned)(t + 1));
  }
}

// ---- out = h1_final @ W_out.T + b_out  (M=128, N=32000, K=512) ----
__global__ void __launch_bounds__(256) k_out(const float* __restrict__ Wout,
                                             const float* __restrict__ bout,
                                             const unsigned short* __restrict__ h1buf,
                                             float* __restrict__ out) {
  const int tid = threadIdx.x, lane = tid & 63, wv = tid >> 6;
  const int l15 = lane & 15, l4 = lane >> 4;
  const int col = blockIdx.x * 64 + wv * 16 + l15;
  const float bo = bout[col];
  f32x4 acc[8];
#pragma unroll
  for (int rt = 0; rt < 8; ++rt) acc[rt] = (f32x4){0.f, 0.f, 0.f, 0.f};
  const unsigned short* h1p1 = h1buf + 8 * GBUF_ELEMS;  // parity-1 = final (t=511)
  const int aoff = l4 * 128 + l15 * 8;
#pragma unroll 4
  for (int s = 0; s < 16; ++s) {
    const f32x4* bp = (const f32x4*)(Wout + (size_t)col * HID + s * 32 + l4 * 8);
    bf16x8 b = cvt8(bp[0], bp[1]);
#pragma unroll
    for (int rt = 0; rt < 8; ++rt) {
      bf16x8 a = *(const bf16x8*)(h1p1 + rt * GBUF_ELEMS + aoff + s * 512);
      acc[rt] = mfma16(a, b, acc[rt]);
    }
  }
#pragma unroll
  for (int rt = 0; rt < 8; ++rt) {
#pragma unroll
    for (int r = 0; r < 4; ++r) {
      int row = rt * 16 + l4 * 4 + r;
      out[(size_t)row * VOCAB + col] = acc[rt][r] + bo;
    }
  }
}

extern "C" void kernel_launch(void* const* d_in, const int* in_sizes, int n_in,
                              void* d_out, int out_size, void* d_ws, size_t ws_size,
                              hipStream_t stream) {
  const int*   X    = (const int*)d_in[0];
  const float* C    = (const float*)d_in[1];
  const float* Wax  = (const float*)d_in[2];
  const float* Waa  = (const float*)d_in[3];
  const float* Wal  = (const float*)d_in[4];
  const float* ba   = (const float*)d_in[5];
  const float* Wout = (const float*)d_in[6];
  const float* bout = (const float*)d_in[7];
  float* out = (float*)d_out;
  char* ws = (char*)d_ws;
  (void)in_sizes; (void)n_in; (void)out_size;

  const size_t cw_bytes = (size_t)VOCAB * HID * 2;          // 32,768,000
  const size_t h_bytes  = 2ull * 8 * GBUF_ELEMS * 2;        // 262,144 (2 parities x 8 groups)
  const size_t off_h0 = cw_bytes;
  const size_t off_h1 = off_h0 + h_bytes;
  const size_t off_fl = off_h1 + h_bytes;
  const size_t fl_bytes = 8 * 32 * 4;                       // 1 KB
  if (ws_size < off_fl + fl_bytes) return;                  // ws too small -> visible failure

  unsigned short* CWp = (unsigned short*)(ws);
  unsigned short* h0  = (unsigned short*)(ws + off_h0);
  unsigned short* h1  = (unsigned short*)(ws + off_h1);
  unsigned*       fl  = (unsigned*)(ws + off_fl);

  const int zero_words = (int)((2 * h_bytes + fl_bytes) / 4);
  hipLaunchKernelGGL(k_init, dim3((zero_words + 255) / 256), dim3(256), 0, stream,
                     (unsigned*)(ws + off_h0), zero_words);
  hipLaunchKernelGGL(k_cw, dim3(VOCAB / 64), dim3(256), 0, stream, C, Wax, CWp);
  hipFuncSetAttribute((const void*)k_scan, hipFuncAttributeMaxDynamicSharedMemorySize, 131072);
  hipLaunchKernelGGL(k_scan, dim3(64), dim3(256), 131072, stream,
                     X, Waa, Wal, ba, CWp, h0, h1, fl);
  hipLaunchKernelGGL(k_out, dim3(VOCAB / 64), dim3(256), 0, stream, Wout, bout, h1, out);
}

// Round 3
// 2225.961 us; speedup vs baseline: 1.8707x; 1.8707x over previous
//
#include <hip/hip_runtime.h>
#include <hip/hip_bf16.h>
#include <stdint.h>

// TextRNN: 2-layer tanh RNN. B=128,T=512,H=512,E=256,V=32000.
//   k_init : zero h-state double buffers + group flags (ws)
//   k_cw   : CW[v][j] = C[v]@W_ax.T (bf16, 32MB ws) -- x-proj hoisted out of the scan
//   k_scan : 8 groups (16 batch rows) x 8 members (64 cols). Weights bf16 in LDS.
//            SKEWED schedule: per step compute h0(t) AND h1(t-1) -> ONE barrier/step (513 total).
//            All cross-block traffic via sc0 sc1 (LLC-coherent, fence-free) inline-asm ops.
//   k_out  : out = h1_final @ W_out.T + b_out
//
// R2 post-mortem: 3.9us/barrier from acquire/release wbl2+invl2 per atomic. Fixed by
// fence-free LLC protocol + halving barrier count via layer skew.

#define VOCAB 32000
#define EMB   256
#define HID   512
#define BATCH 128
#define SEQ   512
#define GBUF_ELEMS 8192   // per-group h buffer: 64 units * 16 rows * 8 = HID*16 bf16

typedef __attribute__((ext_vector_type(8))) short bf16x8;
typedef __attribute__((ext_vector_type(4))) float f32x4;

__device__ inline short f2bf(float f) {
  union { float f; uint32_t u; } v; v.f = f;
  uint32_t u = v.u;
  uint32_t r = (u + 0x7FFFu + ((u >> 16) & 1u)) >> 16;
  return (short)r;
}
__device__ inline float bf2f(unsigned short s) {
  union { uint32_t u; float f; } v; v.u = ((uint32_t)s) << 16;
  return v.f;
}
__device__ inline bf16x8 cvt8(f32x4 x0, f32x4 x1) {
  bf16x8 r;
  r[0]=f2bf(x0[0]); r[1]=f2bf(x0[1]); r[2]=f2bf(x0[2]); r[3]=f2bf(x0[3]);
  r[4]=f2bf(x1[0]); r[5]=f2bf(x1[1]); r[6]=f2bf(x1[2]); r[7]=f2bf(x1[3]);
  return r;
}
__device__ inline f32x4 mfma16(bf16x8 a, bf16x8 b, f32x4 c) {
  return __builtin_amdgcn_mfma_f32_16x16x32_bf16(a, b, c, 0, 0, 0);
}
__device__ inline float fast_tanh(float x) {
  x = fminf(30.f, fmaxf(-30.f, x));
  float e = __expf(2.f * x);
  return (e - 1.f) * __builtin_amdgcn_rcpf(e + 1.f);
}

__global__ void k_init(unsigned* __restrict__ p, int n) {
  int i = blockIdx.x * 256 + threadIdx.x;
  if (i < n) p[i] = 0u;
}

// ---- CW = C @ W_ax.T  (M=32000, N=512, K=256), bf16 out ----
__global__ void __launch_bounds__(256) k_cw(const float* __restrict__ C,
                                            const float* __restrict__ Wax,
                                            unsigned short* __restrict__ CW) {
  const int tid = threadIdx.x, lane = tid & 63, wv = tid >> 6;
  const int l15 = lane & 15, l4 = lane >> 4;
  const int row = blockIdx.x * 64 + wv * 16 + l15;
  bf16x8 a[8];
  const float* crow = C + (size_t)row * EMB;
#pragma unroll
  for (int s = 0; s < 8; ++s) {
    const f32x4* p = (const f32x4*)(crow + s * 32 + l4 * 8);
    a[s] = cvt8(p[0], p[1]);
  }
  const int row_o_base = blockIdx.x * 64 + wv * 16 + l4 * 4;
  for (int ct = 0; ct < 8; ++ct) {
    f32x4 acc[4];
#pragma unroll
    for (int nf = 0; nf < 4; ++nf) acc[nf] = (f32x4){0.f, 0.f, 0.f, 0.f};
#pragma unroll
    for (int s = 0; s < 8; ++s) {
#pragma unroll
      for (int nf = 0; nf < 4; ++nf) {
        int col = ct * 64 + nf * 16 + l15;
        const f32x4* bp = (const f32x4*)(Wax + (size_t)col * EMB + s * 32 + l4 * 8);
        bf16x8 b = cvt8(bp[0], bp[1]);
        acc[nf] = mfma16(a[s], b, acc[nf]);
      }
    }
#pragma unroll
    for (int nf = 0; nf < 4; ++nf) {
      int col = ct * 64 + nf * 16 + l15;
#pragma unroll
      for (int r = 0; r < 4; ++r)
        CW[(size_t)(row_o_base + r) * HID + col] = (unsigned short)f2bf(acc[nf][r]);
    }
  }
}

// ---- the recurrent scan (skewed, fence-free LLC protocol) ----
__global__ void __launch_bounds__(256, 1) k_scan(
    const int* __restrict__ X, const float* __restrict__ Waa, const float* __restrict__ Wal,
    const float* __restrict__ ba, const unsigned short* __restrict__ CW,
    unsigned short* __restrict__ h0buf, unsigned short* __restrict__ h1buf,
    unsigned* __restrict__ flags) {
  extern __shared__ unsigned short lds[];
  unsigned short* ldsWaa = lds;              // [64][512] bf16, 16B-unit swizzled
  unsigned short* ldsWal = lds + 64 * 512;
  unsigned short* sh     = lds + 2 * 64 * 512;  // 2048 shorts: [h0 1024][h1 1024] pack stage
  const int tid = threadIdx.x, lane = tid & 63, wv = tid >> 6;
  const int l15 = lane & 15, l4 = lane >> 4;
  const int g = blockIdx.x & 7, mem = blockIdx.x >> 3;  // group -> same XCD (b%8 heuristic)
  const int colslice = mem * 64;

  // stage weight slices (rows colslice..colslice+63) f32 -> bf16 LDS, swizzled
  for (int c = tid; c < 64 * 64; c += 256) {
    int row = c >> 6, u = c & 63, us = u ^ (row & 7);
    {
      const f32x4* p = (const f32x4*)(Waa + (size_t)(colslice + row) * HID + u * 8);
      *(bf16x8*)(ldsWaa + row * 512 + us * 8) = cvt8(p[0], p[1]);
    }
    {
      const f32x4* p = (const f32x4*)(Wal + (size_t)(colslice + row) * HID + u * 8);
      *(bf16x8*)(ldsWal + row * 512 + us * 8) = cvt8(p[0], p[1]);
    }
  }
  const int jloc = colslice + wv * 16 + l15;   // this lane's output col (0..511)
  const float bav = ba[jloc];
  const int wrow = wv * 16 + l15;              // LDS weight row (0..63)
  const int wbase = wrow * 512;
  const int wswz = wrow & 7;
  const int aoff = l4 * 128 + l15 * 8;         // A-frag per-lane offset (elems)
  const int shoff = (wrow >> 3) * 128 + (wrow & 7);  // LDS pack write base (+ (l4*4+r)*8)
  const int tid2 = tid & 127;
  unsigned* fl = flags + g * 32;
  unsigned short* h0g = h0buf + g * GBUF_ELEMS;
  unsigned short* h1g = h1buf + g * GBUF_ELEMS;
  const int brow0 = g * 16 + l4 * 4;           // batch rows covered by this lane's D regs
  __syncthreads();

  for (int t = 0; t <= SEQ; ++t) {
    const int par = t & 1, parp = par ^ 1;

    // (A) issue cw gather early (plain cached loads via asm; drained by poll's vmcnt(0))
    unsigned cwv[4];
    if (t < SEQ) {
#pragma unroll
      for (int r = 0; r < 4; ++r) {
        int idx = X[(size_t)(brow0 + r) * SEQ + t];
        const unsigned short* cp = CW + (size_t)idx * HID + jloc;
        asm volatile("global_load_ushort %0, %1, off" : "=v"(cwv[r]) : "v"(cp) : "memory");
      }
    }

    // (B) barrier: all members published step t-1 (flag >= t). LLC loads, no cache fences.
    {
      const unsigned target = (unsigned)t;
      unsigned v = 0;
      bool ok = (lane >= 8);
      const unsigned* fp = fl + (lane & 7);
      int guard = 0;
      while (true) {
        if (!ok) {
          asm volatile("global_load_dword %0, %1, off sc0 sc1\n\ts_waitcnt vmcnt(0)"
                       : "=v"(v) : "v"(fp) : "memory");
          ok = (v >= target);
        }
        if (__ballot(ok) == 0xFFFFFFFFFFFFFFFFull) break;
        __builtin_amdgcn_s_sleep(1);
        if (++guard > 1000000) break;   // fail visibly, never hang the harness
      }
    }

    // (C) A-operand loads from LLC: a0 = h0(t-1) [parity parp], a2 = h1(t-2) [parity par]
    bf16x8 a0[16], a2[16];
    const char* pa0 = (const char*)(h0g + parp * (8 * GBUF_ELEMS) + aoff);
    const char* pa2 = (const char*)(h1g + par  * (8 * GBUF_ELEMS) + aoff);
#pragma unroll
    for (int s = 0; s < 16; ++s)
      asm volatile("global_load_dwordx4 %0, %1, off sc0 sc1"
                   : "=v"(a0[s]) : "v"(pa0 + s * 1024) : "memory");
#pragma unroll
    for (int s = 0; s < 16; ++s)
      asm volatile("global_load_dwordx4 %0, %1, off sc0 sc1"
                   : "=v"(a2[s]) : "v"(pa2 + s * 1024) : "memory");

    asm volatile("s_waitcnt vmcnt(16)" ::: "memory");   // a0 (and cw) complete
    __builtin_amdgcn_sched_barrier(0);

    f32x4 acc0 = (f32x4){0.f, 0.f, 0.f, 0.f};
    f32x4 acc1 = (f32x4){0.f, 0.f, 0.f, 0.f};
    if (t < SEQ) {
#pragma unroll
      for (int s = 0; s < 16; ++s) {
        bf16x8 b = *(const bf16x8*)(ldsWaa + wbase + (((s * 4 + l4) ^ wswz) * 8));
        acc0 = mfma16(a0[s], b, acc0);
      }
    }
    if (t >= 1) {
#pragma unroll
      for (int s = 0; s < 16; ++s) {
        bf16x8 b = *(const bf16x8*)(ldsWal + wbase + (((s * 4 + l4) ^ wswz) * 8));
        acc1 = mfma16(a0[s], b, acc1);
      }
    }
    asm volatile("s_waitcnt vmcnt(0)" ::: "memory");    // a2 complete
    __builtin_amdgcn_sched_barrier(0);
    if (t >= 1) {
#pragma unroll
      for (int s = 0; s < 16; ++s) {
        bf16x8 b = *(const bf16x8*)(ldsWaa + wbase + (((s * 4 + l4) ^ wswz) * 8));
        acc1 = mfma16(a2[s], b, acc1);
      }
    }

    // (E) tanh + LDS pack (A-frag layout within block slice)
    if (t < SEQ) {
#pragma unroll
      for (int r = 0; r < 4; ++r) {
        float h = fast_tanh(acc0[r] + bf2f((unsigned short)cwv[r]) + bav);
        sh[shoff + (l4 * 4 + r) * 8] = (unsigned short)f2bf(h);
      }
    }
    if (t >= 1) {
#pragma unroll
      for (int r = 0; r < 4; ++r) {
        float h = fast_tanh(acc1[r] + bav);
        sh[1024 + shoff + (l4 * 4 + r) * 8] = (unsigned short)f2bf(h);
      }
    }
    __syncthreads();

    // (F) packed 16B write-through stores: h0(t)->parity par, h1(t-1)->parity parp
    {
      bool doit = (tid < 128) ? (t < SEQ) : (t >= 1);
      if (doit) {
        bf16x8 vv = *(const bf16x8*)(sh + tid * 8);
        unsigned short* dst = (tid < 128)
            ? (h0g + par  * (8 * GBUF_ELEMS) + mem * 1024 + tid2 * 8)
            : (h1g + parp * (8 * GBUF_ELEMS) + mem * 1024 + tid2 * 8);
        asm volatile("global_store_dwordx4 %0, %1, off sc0 sc1"
                     :: "v"(dst), "v"(vv) : "memory");
      }
    }
    asm volatile("s_waitcnt vmcnt(0)" ::: "memory");    // h stores at LLC before flag
    __syncthreads();                                     // all waves' stores drained
    if (tid == 0)
      asm volatile("global_store_dword %0, %1, off sc0 sc1"
                   :: "v"(fl + mem), "v"((unsigned)(t + 1)) : "memory");
  }
}

// ---- out = h1_final @ W_out.T + b_out  (M=128, N=32000, K=512) ----
__global__ void __launch_bounds__(256) k_out(const float* __restrict__ Wout,
                                             const float* __restrict__ bout,
                                             const unsigned short* __restrict__ h1buf,
                                             float* __restrict__ out) {
  const int tid = threadIdx.x, lane = tid & 63, wv = tid >> 6;
  const int l15 = lane & 15, l4 = lane >> 4;
  const int col = blockIdx.x * 64 + wv * 16 + l15;
  const float bo = bout[col];
  f32x4 acc[8];
#pragma unroll
  for (int rt = 0; rt < 8; ++rt) acc[rt] = (f32x4){0.f, 0.f, 0.f, 0.f};
  const unsigned short* h1p1 = h1buf + 8 * GBUF_ELEMS;  // parity-1 = final h1(511)
  const int aoff = l4 * 128 + l15 * 8;
#pragma unroll 4
  for (int s = 0; s < 16; ++s) {
    const f32x4* bp = (const f32x4*)(Wout + (size_t)col * HID + s * 32 + l4 * 8);
    bf16x8 b = cvt8(bp[0], bp[1]);
#pragma unroll
    for (int rt = 0; rt < 8; ++rt) {
      bf16x8 a = *(const bf16x8*)(h1p1 + rt * GBUF_ELEMS + aoff + s * 512);
      acc[rt] = mfma16(a, b, acc[rt]);
    }
  }
#pragma unroll
  for (int rt = 0; rt < 8; ++rt) {
#pragma unroll
    for (int r = 0; r < 4; ++r) {
      int row = rt * 16 + l4 * 4 + r;
      out[(size_t)row * VOCAB + col] = acc[rt][r] + bo;
    }
  }
}

extern "C" void kernel_launch(void* const* d_in, const int* in_sizes, int n_in,
                              void* d_out, int out_size, void* d_ws, size_t ws_size,
                              hipStream_t stream) {
  const int*   X    = (const int*)d_in[0];
  const float* C    = (const float*)d_in[1];
  const float* Wax  = (const float*)d_in[2];
  const float* Waa  = (const float*)d_in[3];
  const float* Wal  = (const float*)d_in[4];
  const float* ba   = (const float*)d_in[5];
  const float* Wout = (const float*)d_in[6];
  const float* bout = (const float*)d_in[7];
  float* out = (float*)d_out;
  char* ws = (char*)d_ws;
  (void)in_sizes; (void)n_in; (void)out_size;

  const size_t cw_bytes = (size_t)VOCAB * HID * 2;          // 32,768,000
  const size_t h_bytes  = 2ull * 8 * GBUF_ELEMS * 2;        // 262,144 (2 parities x 8 groups)
  const size_t off_h0 = cw_bytes;
  const size_t off_h1 = off_h0 + h_bytes;
  const size_t off_fl = off_h1 + h_bytes;
  const size_t fl_bytes = 8 * 32 * 4;                       // 1 KB
  if (ws_size < off_fl + fl_bytes) return;                  // ws too small -> visible failure

  unsigned short* CWp = (unsigned short*)(ws);
  unsigned short* h0  = (unsigned short*)(ws + off_h0);
  unsigned short* h1  = (unsigned short*)(ws + off_h1);
  unsigned*       fl  = (unsigned*)(ws + off_fl);

  const int zero_words = (int)((2 * h_bytes + fl_bytes) / 4);
  hipLaunchKernelGGL(k_init, dim3((zero_words + 255) / 256), dim3(256), 0, stream,
                     (unsigned*)(ws + off_h0), zero_words);
  hipLaunchKernelGGL(k_cw, dim3(VOCAB / 64), dim3(256), 0, stream, C, Wax, CWp);
  hipFuncSetAttribute((const void*)k_scan, hipFuncAttributeMaxDynamicSharedMemorySize, 135168);
  hipLaunchKernelGGL(k_scan, dim3(64), dim3(256), 135168, stream,
                     X, Waa, Wal, ba, CWp, h0, h1, fl);
  hipLaunchKernelGGL(k_out, dim3(VOCAB / 64), dim3(256), 0, stream, Wout, bout, h1, out);
}